// Round 1
// baseline (1022.232 us; speedup 1.0000x reference)
//
#include <hip/hip_runtime.h>

#define DIN 2048
#define NH 16
#define DH 128
#define SEQ 2048
#define BB 2
#define N3 6144
#define MM 4096  // BB*SEQ

typedef __bf16 bf16;
typedef __attribute__((ext_vector_type(8))) __bf16 bf16x8;
typedef __attribute__((ext_vector_type(4))) float f32x4;

__device__ __forceinline__ f32x4 mfma16(bf16x8 a, bf16x8 b, f32x4 c) {
  return __builtin_amdgcn_mfma_f32_16x16x32_bf16(a, b, c, 0, 0, 0);
}

__device__ __forceinline__ void async16(const void* g, void* l) {
  __builtin_amdgcn_global_load_lds((const __attribute__((address_space(1))) void*)g,
                                   (__attribute__((address_space(3))) void*)l, 16, 0, 0);
}

// ---------------- dtype sniff ----------------
// If storage is bf16, every even-indexed u16 is a bf16 of ~N(0,1): exponent
// field concentrated near 126. If fp32, even u16s are low mantissa bits
// (uniform). Count exponents in a plausible band.
__global__ void sniff_k(const unsigned short* __restrict__ x, int* __restrict__ flag) {
  __shared__ int cnt;
  if (threadIdx.x == 0) cnt = 0;
  __syncthreads();
  unsigned short u = x[threadIdx.x * 2];
  int e = (u >> 7) & 0xff;
  if (e >= 108 && e <= 140) atomicAdd(&cnt, 1);
  __syncthreads();
  if (threadIdx.x == 0) *flag = (cnt >= 128) ? 1 : 0;
}

// ---------------- casts ----------------
__global__ __launch_bounds__(256) void cast_x_k(const void* __restrict__ in, bf16* __restrict__ out,
                                                const int* __restrict__ flag) {
  size_t i = ((size_t)blockIdx.x * 256 + threadIdx.x) * 8;
  if (*flag) {
    *(bf16x8*)(out + i) = *(const bf16x8*)((const bf16*)in + i);
  } else {
    const float* f = (const float*)in;
    bf16x8 v;
    for (int j = 0; j < 8; j++) v[j] = (bf16)f[i + j];
    *(bf16x8*)(out + i) = v;
  }
}

// in: R x C row-major (any of bf16/fp32), out: C x R bf16 (transposed)
__global__ __launch_bounds__(256) void cast_wT_k(const void* __restrict__ in, bf16* __restrict__ out,
                                                 const int* __restrict__ flag, int R, int C) {
  __shared__ float t[32][33];
  int c0 = blockIdx.x * 32, r0 = blockIdx.y * 32;
  int tx = threadIdx.x & 31, ty = threadIdx.x >> 5;
  bool isb = *flag != 0;
  for (int j = 0; j < 4; j++) {
    int r = ty + j * 8;
    size_t idx = (size_t)(r0 + r) * C + c0 + tx;
    float v = isb ? (float)((const bf16*)in)[idx] : ((const float*)in)[idx];
    t[r][tx] = v;
  }
  __syncthreads();
  for (int j = 0; j < 4; j++) {
    int c = ty + j * 8;
    out[(size_t)(c0 + c) * R + r0 + tx] = (bf16)t[tx][c];
  }
}

// ---------------- qkv GEMM: Xb(4096x2048) @ WqkvT(6144x2048)^T -> Q/K/V (B,H,S,DH) bf16
__global__ __launch_bounds__(256) void gemm_qkv_k(const bf16* __restrict__ A, const bf16* __restrict__ BT,
                                                  bf16* __restrict__ Qb, bf16* __restrict__ Kb,
                                                  bf16* __restrict__ Vb) {
  __shared__ __align__(16) bf16 As[128 * 32];
  __shared__ __align__(16) bf16 Bs[128 * 32];
  const int K = DIN;
  int m0 = blockIdx.y * 128, n0 = blockIdx.x * 128;
  int tid = threadIdx.x, w = tid >> 6, l = tid & 63;
  int l15 = l & 15, quad = l >> 4;
  int wm = (w & 1) * 64, wn = (w >> 1) * 64;
  f32x4 zero = {0.f, 0.f, 0.f, 0.f};
  f32x4 acc[4][4];
  for (int i = 0; i < 4; i++)
    for (int j = 0; j < 4; j++) acc[i][j] = zero;
  const bf16* Ag = A + (size_t)(m0 + w * 32 + (l >> 2)) * K + (l & 3) * 8;
  const bf16* Bg = BT + (size_t)(n0 + w * 32 + (l >> 2)) * K + (l & 3) * 8;
  bf16* AsW = As + (w * 32) * 32;
  bf16* BsW = Bs + (w * 32) * 32;
  for (int k0 = 0; k0 < K; k0 += 32) {
    __syncthreads();
    async16(Ag + k0, AsW);
    async16(Ag + k0 + 16 * K, AsW + 16 * 32);
    async16(Bg + k0, BsW);
    async16(Bg + k0 + 16 * K, BsW + 16 * 32);
    __syncthreads();
    bf16x8 af[4], bfv[4];
    for (int i = 0; i < 4; i++) af[i] = *(const bf16x8*)&As[(wm + i * 16 + l15) * 32 + quad * 8];
    for (int j = 0; j < 4; j++) bfv[j] = *(const bf16x8*)&Bs[(wn + j * 16 + l15) * 32 + quad * 8];
    for (int i = 0; i < 4; i++)
      for (int j = 0; j < 4; j++) acc[i][j] = mfma16(af[i], bfv[j], acc[i][j]);
  }
  // epilogue: scatter to Q/K/V in (B,H,S,DH)
  for (int j = 0; j < 4; j++) {
    int col = n0 + wn + j * 16 + l15;
    int part = col >> 11, cw = col & 2047;
    int h = cw >> 7, d = cw & 127;
    bf16* dst = (part == 0) ? Qb : ((part == 1) ? Kb : Vb);
    for (int i = 0; i < 4; i++) {
      int mrow = m0 + wm + i * 16 + quad * 4;
      for (int r = 0; r < 4; r++) {
        int m = mrow + r;
        int b = m >> 11, s = m & 2047;
        dst[(((size_t)(b * NH + h)) * SEQ + s) * DH + d] = (bf16)acc[i][j][r];
      }
    }
  }
}

// ---------------- RoPE (and fold 1/sqrt(DH) into Q) ----------------
__global__ __launch_bounds__(256) void rope_k(bf16* __restrict__ Qb, bf16* __restrict__ Kb) {
  int i = blockIdx.x * 256 + threadIdx.x;  // (bh, s, d2): 32*2048*64
  int d2 = i & 63;
  int s = (i >> 6) & 2047;
  int bh = i >> 17;
  float invf = expf(-9.210340371976184f * (float)(2 * d2) * (1.0f / 128.0f));
  float ang = (float)s * invf;
  float sn, cs;
  sincosf(ang, &sn, &cs);
  size_t base = ((size_t)bh * SEQ + s) * DH + 2 * d2;
  const float scale = 0.08838834764831845f;  // DH^-0.5
  float q1 = (float)Qb[base], q2 = (float)Qb[base + 1];
  Qb[base] = (bf16)((q1 * cs - q2 * sn) * scale);
  Qb[base + 1] = (bf16)((q1 * sn + q2 * cs) * scale);
  float k1 = (float)Kb[base], k2 = (float)Kb[base + 1];
  Kb[base] = (bf16)(k1 * cs - k2 * sn);
  Kb[base + 1] = (bf16)(k1 * sn + k2 * cs);
}

// ---------------- V transpose: (B,H,S,DH) -> (B,H,DH,S) ----------------
__global__ __launch_bounds__(256) void transpose_v_k(const bf16* __restrict__ V, bf16* __restrict__ Vt) {
  __shared__ float t[32][33];
  int s0 = blockIdx.x * 32, d0 = blockIdx.y * 32;
  int bh = blockIdx.z;
  const bf16* Vp = V + (size_t)bh * SEQ * DH;
  bf16* Vo = Vt + (size_t)bh * DH * SEQ;
  int tx = threadIdx.x & 31, ty = threadIdx.x >> 5;
  for (int j = 0; j < 4; j++)
    t[ty + j * 8][tx] = (float)Vp[(size_t)(s0 + ty + j * 8) * DH + d0 + tx];
  __syncthreads();
  for (int j = 0; j < 4; j++)
    Vo[(size_t)(d0 + ty + j * 8) * SEQ + s0 + tx] = (bf16)t[tx][ty + j * 8];
}

// ---------------- flash attention ----------------
// grid: B*NH*(SEQ/64) blocks, 4 waves/block; wave w owns q rows [tile*64+w*16, +16)
__global__ __launch_bounds__(256) void attn_k(const bf16* __restrict__ Qb, const bf16* __restrict__ Kb,
                                              const bf16* __restrict__ Vt, bf16* __restrict__ Yb) {
  __shared__ __align__(16) bf16 Pl[4][16 * 72];
  int tile = blockIdx.x & 31, bh = blockIdx.x >> 5;
  int w = threadIdx.x >> 6, l = threadIdx.x & 63;
  int l15 = l & 15, quad = l >> 4;
  int q0 = tile * 64 + w * 16;
  const bf16* Qp = Qb + (size_t)bh * SEQ * DH;
  const bf16* Kp = Kb + (size_t)bh * SEQ * DH;
  const bf16* Vp = Vt + (size_t)bh * DH * SEQ;
  bf16* P = &Pl[w][0];
  bf16x8 qf[4];
  for (int kc = 0; kc < 4; kc++)
    qf[kc] = *(const bf16x8*)&Qp[(size_t)(q0 + l15) * DH + kc * 32 + quad * 8];
  f32x4 zero = {0.f, 0.f, 0.f, 0.f};
  f32x4 o[8];
  for (int n = 0; n < 8; n++) o[n] = zero;
  float mprev[4] = {-1e30f, -1e30f, -1e30f, -1e30f};
  float lsum[4] = {0.f, 0.f, 0.f, 0.f};
  const float L2E = 1.4426950408889634f;
  for (int k0 = 0; k0 <= q0 + 15; k0 += 64) {
    f32x4 sc[4];
    for (int n = 0; n < 4; n++) sc[n] = zero;
    for (int ns = 0; ns < 4; ns++)
      for (int kc = 0; kc < 4; kc++) {
        bf16x8 kf = *(const bf16x8*)&Kp[(size_t)(k0 + ns * 16 + l15) * DH + kc * 32 + quad * 8];
        sc[ns] = mfma16(qf[kc], kf, sc[ns]);
      }
    if (k0 + 63 > q0) {  // only last tile needs causal mask
      for (int ns = 0; ns < 4; ns++) {
        int col = k0 + ns * 16 + l15;
        for (int r = 0; r < 4; r++)
          if (col > q0 + quad * 4 + r) sc[ns][r] = -1e30f;
      }
    }
    float rmax[4], mnew[4], alpha[4], rs[4];
    for (int r = 0; r < 4; r++)
      rmax[r] = fmaxf(fmaxf(sc[0][r], sc[1][r]), fmaxf(sc[2][r], sc[3][r]));
    for (int off = 1; off < 16; off <<= 1)
      for (int r = 0; r < 4; r++) rmax[r] = fmaxf(rmax[r], __shfl_xor(rmax[r], off, 64));
    for (int r = 0; r < 4; r++) {
      mnew[r] = fmaxf(mprev[r], rmax[r]);
      alpha[r] = exp2f((mprev[r] - mnew[r]) * L2E);
      mprev[r] = mnew[r];
    }
    for (int ns = 0; ns < 4; ns++)
      for (int r = 0; r < 4; r++) sc[ns][r] = exp2f((sc[ns][r] - mnew[r]) * L2E);
    for (int r = 0; r < 4; r++) rs[r] = (sc[0][r] + sc[1][r]) + (sc[2][r] + sc[3][r]);
    for (int off = 1; off < 16; off <<= 1)
      for (int r = 0; r < 4; r++) rs[r] += __shfl_xor(rs[r], off, 64);
    f32x4 av;
    for (int r = 0; r < 4; r++) {
      lsum[r] = lsum[r] * alpha[r] + rs[r];
      av[r] = alpha[r];
    }
    for (int n = 0; n < 8; n++) o[n] *= av;
    // P: C-layout -> LDS -> A-layout (bf16)
    for (int ns = 0; ns < 4; ns++)
      for (int r = 0; r < 4; r++)
        P[(quad * 4 + r) * 72 + ns * 16 + l15] = (bf16)sc[ns][r];
    asm volatile("s_waitcnt lgkmcnt(0)" ::: "memory");
    bf16x8 pa[2];
    for (int kc = 0; kc < 2; kc++)
      pa[kc] = *(const bf16x8*)&P[l15 * 72 + kc * 32 + quad * 8];
    for (int ns = 0; ns < 8; ns++)
      for (int kc = 0; kc < 2; kc++) {
        bf16x8 vf = *(const bf16x8*)&Vp[(size_t)(ns * 16 + l15) * SEQ + k0 + kc * 32 + quad * 8];
        o[ns] = mfma16(pa[kc], vf, o[ns]);
      }
  }
  int b = bh >> 4, h = bh & 15;
  for (int r = 0; r < 4; r++) {
    float inv = 1.0f / lsum[r];
    int s = q0 + quad * 4 + r;
    size_t base = ((size_t)(b * SEQ + s)) * DIN + h * DH;
    for (int ns = 0; ns < 8; ns++)
      Yb[base + ns * 16 + l15] = (bf16)(o[ns][r] * inv);
  }
}

// ---------------- proj GEMM: Yb(4096x2048) @ WprojT(2048x2048)^T -> out ----------------
__global__ __launch_bounds__(256) void gemm_proj_k(const bf16* __restrict__ A, const bf16* __restrict__ BT,
                                                   void* __restrict__ out, const int* __restrict__ flag) {
  __shared__ __align__(16) bf16 As[128 * 32];
  __shared__ __align__(16) bf16 Bs[128 * 32];
  const int K = DIN;
  int m0 = blockIdx.y * 128, n0 = blockIdx.x * 128;
  int tid = threadIdx.x, w = tid >> 6, l = tid & 63;
  int l15 = l & 15, quad = l >> 4;
  int wm = (w & 1) * 64, wn = (w >> 1) * 64;
  bool obf = *flag != 0;
  f32x4 zero = {0.f, 0.f, 0.f, 0.f};
  f32x4 acc[4][4];
  for (int i = 0; i < 4; i++)
    for (int j = 0; j < 4; j++) acc[i][j] = zero;
  const bf16* Ag = A + (size_t)(m0 + w * 32 + (l >> 2)) * K + (l & 3) * 8;
  const bf16* Bg = BT + (size_t)(n0 + w * 32 + (l >> 2)) * K + (l & 3) * 8;
  bf16* AsW = As + (w * 32) * 32;
  bf16* BsW = Bs + (w * 32) * 32;
  for (int k0 = 0; k0 < K; k0 += 32) {
    __syncthreads();
    async16(Ag + k0, AsW);
    async16(Ag + k0 + 16 * K, AsW + 16 * 32);
    async16(Bg + k0, BsW);
    async16(Bg + k0 + 16 * K, BsW + 16 * 32);
    __syncthreads();
    bf16x8 af[4], bfv[4];
    for (int i = 0; i < 4; i++) af[i] = *(const bf16x8*)&As[(wm + i * 16 + l15) * 32 + quad * 8];
    for (int j = 0; j < 4; j++) bfv[j] = *(const bf16x8*)&Bs[(wn + j * 16 + l15) * 32 + quad * 8];
    for (int i = 0; i < 4; i++)
      for (int j = 0; j < 4; j++) acc[i][j] = mfma16(af[i], bfv[j], acc[i][j]);
  }
  for (int j = 0; j < 4; j++) {
    int col = n0 + wn + j * 16 + l15;
    for (int i = 0; i < 4; i++) {
      int mrow = m0 + wm + i * 16 + quad * 4;
      for (int r = 0; r < 4; r++) {
        size_t idx = (size_t)(mrow + r) * DIN + col;
        float v = acc[i][j][r];
        if (obf)
          ((bf16*)out)[idx] = (bf16)v;
        else
          ((float*)out)[idx] = v;
      }
    }
  }
}

extern "C" void kernel_launch(void* const* d_in, const int* in_sizes, int n_in,
                              void* d_out, int out_size, void* d_ws, size_t ws_size,
                              hipStream_t stream) {
  char* ws = (char*)d_ws;
  int* flag = (int*)ws;
  bf16* Xb = (bf16*)(ws + 256);                                  // 16 MiB, aliased with Yb
  bf16* WqkvT = (bf16*)(ws + 256 + 16777216);                    // 24 MiB
  bf16* WprojT = (bf16*)(ws + 256 + 16777216 + 25165824);        // 8 MiB
  bf16* Qb = (bf16*)(ws + 256 + 16777216 + 25165824 + 8388608);  // 16 MiB each
  bf16* Kb = Qb + (size_t)MM * DIN;
  bf16* Vb = Kb + (size_t)MM * DIN;
  bf16* Vt = Vb + (size_t)MM * DIN;
  bf16* Yb = Xb;  // Xb dead after gemm_qkv

  sniff_k<<<1, 256, 0, stream>>>((const unsigned short*)d_in[0], flag);
  cast_x_k<<<4096, 256, 0, stream>>>(d_in[0], Xb, flag);
  cast_wT_k<<<dim3(192, 64), 256, 0, stream>>>(d_in[1], WqkvT, flag, DIN, N3);
  cast_wT_k<<<dim3(64, 64), 256, 0, stream>>>(d_in[2], WprojT, flag, DIN, DIN);
  gemm_qkv_k<<<dim3(48, 32), 256, 0, stream>>>(Xb, WqkvT, Qb, Kb, Vb);
  rope_k<<<16384, 256, 0, stream>>>(Qb, Kb);
  transpose_v_k<<<dim3(64, 4, 32), 256, 0, stream>>>(Vb, Vt);
  attn_k<<<1024, 256, 0, stream>>>(Qb, Kb, Vt, Yb);
  gemm_proj_k<<<dim3(16, 32), 256, 0, stream>>>(Yb, WprojT, d_out, flag);
}

// Round 2
// 476.913 us; speedup vs baseline: 2.1434x; 2.1434x over previous
//
#include <hip/hip_runtime.h>

#define DIN 2048
#define NH 16
#define DH 128
#define SEQ 2048
#define BB 2
#define N3 6144
#define MM 4096  // BB*SEQ

typedef __bf16 bf16;
typedef __attribute__((ext_vector_type(8))) __bf16 bf16x8;
typedef __attribute__((ext_vector_type(4))) __bf16 bf16x4;
typedef __attribute__((ext_vector_type(4))) float f32x4;

__device__ __forceinline__ f32x4 mfma16(bf16x8 a, bf16x8 b, f32x4 c) {
  return __builtin_amdgcn_mfma_f32_16x16x32_bf16(a, b, c, 0, 0, 0);
}

__device__ __forceinline__ void async16(const void* g, void* l) {
  __builtin_amdgcn_global_load_lds((const __attribute__((address_space(1))) void*)g,
                                   (__attribute__((address_space(3))) void*)l, 16, 0, 0);
}

// ---------------- dtype sniff ----------------
__global__ void sniff_k(const unsigned short* __restrict__ x, int* __restrict__ flag) {
  __shared__ int cnt;
  if (threadIdx.x == 0) cnt = 0;
  __syncthreads();
  unsigned short u = x[threadIdx.x * 2];
  int e = (u >> 7) & 0xff;
  if (e >= 108 && e <= 140) atomicAdd(&cnt, 1);
  __syncthreads();
  if (threadIdx.x == 0) *flag = (cnt >= 128) ? 1 : 0;
}

// ---------------- casts ----------------
__global__ __launch_bounds__(256) void cast_x_k(const void* __restrict__ in, bf16* __restrict__ out,
                                                const int* __restrict__ flag) {
  size_t i = ((size_t)blockIdx.x * 256 + threadIdx.x) * 8;
  if (*flag) {
    *(bf16x8*)(out + i) = *(const bf16x8*)((const bf16*)in + i);
  } else {
    const float* f = (const float*)in;
    bf16x8 v;
    for (int j = 0; j < 8; j++) v[j] = (bf16)f[i + j];
    *(bf16x8*)(out + i) = v;
  }
}

__global__ __launch_bounds__(256) void cast_wT_k(const void* __restrict__ in, bf16* __restrict__ out,
                                                 const int* __restrict__ flag, int R, int C) {
  __shared__ float t[32][33];
  int c0 = blockIdx.x * 32, r0 = blockIdx.y * 32;
  int tx = threadIdx.x & 31, ty = threadIdx.x >> 5;
  bool isb = *flag != 0;
  for (int j = 0; j < 4; j++) {
    int r = ty + j * 8;
    size_t idx = (size_t)(r0 + r) * C + c0 + tx;
    float v = isb ? (float)((const bf16*)in)[idx] : ((const float*)in)[idx];
    t[r][tx] = v;
  }
  __syncthreads();
  for (int j = 0; j < 4; j++) {
    int c = ty + j * 8;
    out[(size_t)(c0 + c) * R + r0 + tx] = (bf16)t[tx][c];
  }
}

// ---------------- qkv GEMM ----------------
// K is written with per-row 16B-chunk xor swizzle: chunk c of row s stored at c^(s&7),
// so attn's DMA-staged LDS tile reads are bank-conflict-free.
__global__ __launch_bounds__(256) void gemm_qkv_k(const bf16* __restrict__ A, const bf16* __restrict__ BT,
                                                  bf16* __restrict__ Qb, bf16* __restrict__ Kb,
                                                  bf16* __restrict__ Vb) {
  __shared__ __align__(16) bf16 As[128 * 32];
  __shared__ __align__(16) bf16 Bs[128 * 32];
  const int K = DIN;
  int m0 = blockIdx.y * 128, n0 = blockIdx.x * 128;
  int tid = threadIdx.x, w = tid >> 6, l = tid & 63;
  int l15 = l & 15, quad = l >> 4;
  int wm = (w & 1) * 64, wn = (w >> 1) * 64;
  f32x4 zero = {0.f, 0.f, 0.f, 0.f};
  f32x4 acc[4][4];
  for (int i = 0; i < 4; i++)
    for (int j = 0; j < 4; j++) acc[i][j] = zero;
  const bf16* Ag = A + (size_t)(m0 + w * 32 + (l >> 2)) * K + (l & 3) * 8;
  const bf16* Bg = BT + (size_t)(n0 + w * 32 + (l >> 2)) * K + (l & 3) * 8;
  bf16* AsW = As + (w * 32) * 32;
  bf16* BsW = Bs + (w * 32) * 32;
  for (int k0 = 0; k0 < K; k0 += 32) {
    __syncthreads();
    async16(Ag + k0, AsW);
    async16(Ag + k0 + 16 * K, AsW + 16 * 32);
    async16(Bg + k0, BsW);
    async16(Bg + k0 + 16 * K, BsW + 16 * 32);
    __syncthreads();
    bf16x8 af[4], bfv[4];
    for (int i = 0; i < 4; i++) af[i] = *(const bf16x8*)&As[(wm + i * 16 + l15) * 32 + quad * 8];
    for (int j = 0; j < 4; j++) bfv[j] = *(const bf16x8*)&Bs[(wn + j * 16 + l15) * 32 + quad * 8];
    for (int i = 0; i < 4; i++)
      for (int j = 0; j < 4; j++) acc[i][j] = mfma16(af[i], bfv[j], acc[i][j]);
  }
  for (int j = 0; j < 4; j++) {
    int col = n0 + wn + j * 16 + l15;
    int part = col >> 11, cw = col & 2047;
    int h = cw >> 7, d = cw & 127;
    bf16* dst = (part == 0) ? Qb : ((part == 1) ? Kb : Vb);
    for (int i = 0; i < 4; i++) {
      int mrow = m0 + wm + i * 16 + quad * 4;
      for (int r = 0; r < 4; r++) {
        int m = mrow + r;
        int b = m >> 11, s = m & 2047;
        int dd = (part == 1) ? (((((d >> 3) ^ (s & 7)) << 3)) | (d & 7)) : d;
        dst[(((size_t)(b * NH + h)) * SEQ + s) * DH + dd] = (bf16)acc[i][j][r];
      }
    }
  }
}

// ---------------- RoPE (scale folded into Q; K is swizzled in memory) ----------------
__global__ __launch_bounds__(256) void rope_k(bf16* __restrict__ Qb, bf16* __restrict__ Kb) {
  int i = blockIdx.x * 256 + threadIdx.x;  // (bh, s, d2): 32*2048*64
  int d2 = i & 63;
  int s = (i >> 6) & 2047;
  int bh = i >> 17;
  int dl = 2 * d2;
  float invf = expf(-9.210340371976184f * (float)dl * (1.0f / 128.0f));
  float ang = (float)s * invf;
  float sn, cs;
  sincosf(ang, &sn, &cs);
  size_t row = ((size_t)bh * SEQ + s) * DH;
  const float scale = 0.08838834764831845f;  // DH^-0.5
  size_t qb = row + dl;
  float q1 = (float)Qb[qb], q2 = (float)Qb[qb + 1];
  Qb[qb] = (bf16)((q1 * cs - q2 * sn) * scale);
  Qb[qb + 1] = (bf16)((q1 * sn + q2 * cs) * scale);
  size_t kb = row + ((((dl >> 3) ^ (s & 7)) << 3) | (dl & 7));
  float k1 = (float)Kb[kb], k2 = (float)Kb[kb + 1];
  Kb[kb] = (bf16)(k1 * cs - k2 * sn);
  Kb[kb + 1] = (bf16)(k1 * sn + k2 * cs);
}

// ---------------- V transpose: (B,H,S,DH) -> (B,H,DH,S), swizzled within 64-col windows
__global__ __launch_bounds__(256) void transpose_v_k(const bf16* __restrict__ V, bf16* __restrict__ Vt) {
  __shared__ float t[32][33];
  int s0 = blockIdx.x * 32, d0 = blockIdx.y * 32;
  int bh = blockIdx.z;
  const bf16* Vp = V + (size_t)bh * SEQ * DH;
  bf16* Vo = Vt + (size_t)bh * DH * SEQ;
  int tx = threadIdx.x & 31, ty = threadIdx.x >> 5;
  for (int j = 0; j < 4; j++)
    t[ty + j * 8][tx] = (float)Vp[(size_t)(s0 + ty + j * 8) * DH + d0 + tx];
  __syncthreads();
  for (int j = 0; j < 4; j++) {
    int dh = d0 + ty + j * 8;
    int s = s0 + tx;
    int sl = s & 63;
    int col = (s & ~63) | ((((sl >> 3) ^ (dh & 7)) << 3) | (sl & 7));
    Vo[(size_t)dh * SEQ + col] = (bf16)t[tx][ty + j * 8];
  }
}

// ---------------- flash attention v2 ----------------
// grid (32 bh, 16 tile-slots). Q-tile 128 (4 waves x 32 rows). K-tile 64, LDS
// double-buffered via global_load_lds; xor-swizzled global layout -> conflict-free b128 reads.
__global__ __launch_bounds__(256) void attn_k(const bf16* __restrict__ Qb, const bf16* __restrict__ Kb,
                                              const bf16* __restrict__ Vt, bf16* __restrict__ Yb) {
  __shared__ __align__(16) bf16 Ks[2][64 * 128];
  __shared__ __align__(16) bf16 Vs[2][128 * 64];
  __shared__ __align__(16) bf16 Pl[4][16 * 72];
  int bh = blockIdx.x;
  int yy = blockIdx.y;
  int tile = (yy < 8) ? yy : (23 - yy);  // pair heavy with light tiles
  int w = threadIdx.x >> 6, l = threadIdx.x & 63;
  int l15 = l & 15, quad = l >> 4;
  int q0 = tile * 128;
  const bf16* Qp = Qb + (size_t)bh * SEQ * DH;
  const bf16* Kp = Kb + (size_t)bh * SEQ * DH;
  const bf16* Vp = Vt + (size_t)bh * DH * SEQ;
  // Q fragments (global layout is plain)
  bf16x8 qf[2][4];
  for (int rb = 0; rb < 2; rb++)
    for (int kc = 0; kc < 4; kc++)
      qf[rb][kc] = *(const bf16x8*)&Qp[(size_t)(q0 + w * 32 + rb * 16 + l15) * DH + kc * 32 + quad * 8];
  f32x4 zero = {0.f, 0.f, 0.f, 0.f};
  f32x4 o[2][8];
  for (int rb = 0; rb < 2; rb++)
    for (int ns = 0; ns < 8; ns++) o[rb][ns] = zero;
  float mprev[2][4], lsum[2][4];
  for (int rb = 0; rb < 2; rb++)
    for (int r = 0; r < 4; r++) { mprev[rb][r] = -1e30f; lsum[rb][r] = 0.f; }
  const float L2E = 1.4426950408889634f;
  int nkt = 2 * tile + 2;

  auto stage = [&](int it, int buf) {
    const char* gk = (const char*)Kp + (size_t)it * 16384 + w * 4096 + l * 16;
    char* lk = (char*)&Ks[buf][0] + w * 4096;
    for (int i = 0; i < 4; i++) async16(gk + i * 1024, lk + i * 1024);
    const char* gv = (const char*)Vp + (size_t)it * 128 + (size_t)(w * 32 + (l >> 3)) * (SEQ * 2) + (l & 7) * 16;
    char* lv = (char*)&Vs[buf][0] + w * 32 * 128;
    for (int i = 0; i < 4; i++) async16(gv + (size_t)i * 8 * (SEQ * 2), lv + i * 1024);
  };

  auto soft_pv = [&](int rb, f32x4* sc, int k0, int buf) {
    int qrb = q0 + w * 32 + rb * 16;
    if (k0 + 63 > qrb) {
      for (int ns = 0; ns < 4; ns++) {
        int col = k0 + ns * 16 + l15;
        for (int r = 0; r < 4; r++)
          if (col > qrb + quad * 4 + r) sc[ns][r] = -1e30f;
      }
    }
    float rmax[4], mnew[4], al[4], rs[4];
    for (int r = 0; r < 4; r++)
      rmax[r] = fmaxf(fmaxf(sc[0][r], sc[1][r]), fmaxf(sc[2][r], sc[3][r]));
    for (int off = 1; off < 16; off <<= 1)
      for (int r = 0; r < 4; r++) rmax[r] = fmaxf(rmax[r], __shfl_xor(rmax[r], off, 64));
    for (int r = 0; r < 4; r++) {
      mnew[r] = fmaxf(mprev[rb][r], rmax[r]);
      al[r] = exp2f((mprev[rb][r] - mnew[r]) * L2E);
      mprev[rb][r] = mnew[r];
    }
    for (int ns = 0; ns < 4; ns++)
      for (int r = 0; r < 4; r++) sc[ns][r] = exp2f((sc[ns][r] - mnew[r]) * L2E);
    for (int r = 0; r < 4; r++) rs[r] = (sc[0][r] + sc[1][r]) + (sc[2][r] + sc[3][r]);
    for (int off = 1; off < 16; off <<= 1)
      for (int r = 0; r < 4; r++) rs[r] += __shfl_xor(rs[r], off, 64);
    for (int r = 0; r < 4; r++) lsum[rb][r] = lsum[rb][r] * al[r] + rs[r];
    // broadcast alpha from (quad,r) rows to per-lane l15 rows (O^T layout)
    int r3 = l15 & 3;
    float asel = (r3 == 0) ? al[0] : (r3 == 1) ? al[1] : (r3 == 2) ? al[2] : al[3];
    float abc = __shfl(asel, ((l15 >> 2) << 4) | r3, 64);
    for (int ns = 0; ns < 8; ns++) o[rb][ns] *= abc;
    // P: C-layout -> LDS -> A/B-fragment layout
    bf16* P = &Pl[w][0];
    for (int ns = 0; ns < 4; ns++)
      for (int r = 0; r < 4; r++)
        P[(quad * 4 + r) * 72 + ns * 16 + l15] = (bf16)sc[ns][r];
    asm volatile("s_waitcnt lgkmcnt(0)" ::: "memory");
    bf16x8 pa[2];
    for (int kc = 0; kc < 2; kc++)
      pa[kc] = *(const bf16x8*)&P[l15 * 72 + kc * 32 + quad * 8];
    for (int ns = 0; ns < 8; ns++)
      for (int kc = 0; kc < 2; kc++) {
        bf16x8 vf = *(const bf16x8*)&Vs[buf][(ns * 16 + l15) * 64 + (((kc * 4 + quad) ^ (l15 & 7)) << 3)];
        o[rb][ns] = mfma16(vf, pa[kc], o[rb][ns]);  // O^T accumulate
      }
  };

  stage(0, 0);
  __syncthreads();
  for (int it = 0; it < nkt; it++) {
    int buf = it & 1;
    if (it + 1 < nkt) stage(it + 1, buf ^ 1);
    int k0 = it * 64;
    bool act1 = (k0 <= q0 + w * 32 + 16 + 15);
    if (act1) {
      f32x4 sc0[4], sc1[4];
      for (int ns = 0; ns < 4; ns++) { sc0[ns] = zero; sc1[ns] = zero; }
      for (int kc = 0; kc < 4; kc++)
        for (int ns = 0; ns < 4; ns++) {
          bf16x8 kf = *(const bf16x8*)&Ks[buf][(ns * 16 + l15) * 128 + (((kc * 4 + quad) ^ (l15 & 7)) << 3)];
          sc0[ns] = mfma16(qf[0][kc], kf, sc0[ns]);
          sc1[ns] = mfma16(qf[1][kc], kf, sc1[ns]);
        }
      if (k0 <= q0 + w * 32 + 15) soft_pv(0, sc0, k0, buf);
      soft_pv(1, sc1, k0, buf);
    }
    __syncthreads();
  }
  // epilogue: O^T layout -> lane l15 owns q row; 8B vector stores
  int b = bh >> 4, h = bh & 15;
  for (int rb = 0; rb < 2; rb++) {
    int r3 = l15 & 3;
    float lsel = (r3 == 0) ? lsum[rb][0] : (r3 == 1) ? lsum[rb][1] : (r3 == 2) ? lsum[rb][2] : lsum[rb][3];
    float lb = __shfl(lsel, ((l15 >> 2) << 4) | r3, 64);
    float inv = 1.0f / lb;
    int q = q0 + w * 32 + rb * 16 + l15;
    size_t base = ((size_t)(b * SEQ + q)) * DIN + h * DH + quad * 4;
    for (int ns = 0; ns < 8; ns++) {
      bf16x4 pk;
      for (int r = 0; r < 4; r++) pk[r] = (bf16)(o[rb][ns][r] * inv);
      *(bf16x4*)&Yb[base + ns * 16] = pk;
    }
  }
}

// ---------------- proj GEMM ----------------
__global__ __launch_bounds__(256) void gemm_proj_k(const bf16* __restrict__ A, const bf16* __restrict__ BT,
                                                   void* __restrict__ out, const int* __restrict__ flag) {
  __shared__ __align__(16) bf16 As[128 * 32];
  __shared__ __align__(16) bf16 Bs[128 * 32];
  const int K = DIN;
  int m0 = blockIdx.y * 128, n0 = blockIdx.x * 128;
  int tid = threadIdx.x, w = tid >> 6, l = tid & 63;
  int l15 = l & 15, quad = l >> 4;
  int wm = (w & 1) * 64, wn = (w >> 1) * 64;
  bool obf = *flag != 0;
  f32x4 zero = {0.f, 0.f, 0.f, 0.f};
  f32x4 acc[4][4];
  for (int i = 0; i < 4; i++)
    for (int j = 0; j < 4; j++) acc[i][j] = zero;
  const bf16* Ag = A + (size_t)(m0 + w * 32 + (l >> 2)) * K + (l & 3) * 8;
  const bf16* Bg = BT + (size_t)(n0 + w * 32 + (l >> 2)) * K + (l & 3) * 8;
  bf16* AsW = As + (w * 32) * 32;
  bf16* BsW = Bs + (w * 32) * 32;
  for (int k0 = 0; k0 < K; k0 += 32) {
    __syncthreads();
    async16(Ag + k0, AsW);
    async16(Ag + k0 + 16 * K, AsW + 16 * 32);
    async16(Bg + k0, BsW);
    async16(Bg + k0 + 16 * K, BsW + 16 * 32);
    __syncthreads();
    bf16x8 af[4], bfv[4];
    for (int i = 0; i < 4; i++) af[i] = *(const bf16x8*)&As[(wm + i * 16 + l15) * 32 + quad * 8];
    for (int j = 0; j < 4; j++) bfv[j] = *(const bf16x8*)&Bs[(wn + j * 16 + l15) * 32 + quad * 8];
    for (int i = 0; i < 4; i++)
      for (int j = 0; j < 4; j++) acc[i][j] = mfma16(af[i], bfv[j], acc[i][j]);
  }
  for (int j = 0; j < 4; j++) {
    int col = n0 + wn + j * 16 + l15;
    for (int i = 0; i < 4; i++) {
      int mrow = m0 + wm + i * 16 + quad * 4;
      for (int r = 0; r < 4; r++) {
        size_t idx = (size_t)(mrow + r) * DIN + col;
        float v = acc[i][j][r];
        if (obf)
          ((bf16*)out)[idx] = (bf16)v;
        else
          ((float*)out)[idx] = v;
      }
    }
  }
}

extern "C" void kernel_launch(void* const* d_in, const int* in_sizes, int n_in,
                              void* d_out, int out_size, void* d_ws, size_t ws_size,
                              hipStream_t stream) {
  char* ws = (char*)d_ws;
  int* flag = (int*)ws;
  bf16* Xb = (bf16*)(ws + 256);                                  // 16 MiB, aliased with Yb
  bf16* WqkvT = (bf16*)(ws + 256 + 16777216);                    // 24 MiB
  bf16* WprojT = (bf16*)(ws + 256 + 16777216 + 25165824);        // 8 MiB
  bf16* Qb = (bf16*)(ws + 256 + 16777216 + 25165824 + 8388608);  // 16 MiB each
  bf16* Kb = Qb + (size_t)MM * DIN;
  bf16* Vb = Kb + (size_t)MM * DIN;
  bf16* Vt = Vb + (size_t)MM * DIN;
  bf16* Yb = Xb;  // Xb dead after gemm_qkv

  sniff_k<<<1, 256, 0, stream>>>((const unsigned short*)d_in[0], flag);
  cast_x_k<<<4096, 256, 0, stream>>>(d_in[0], Xb, flag);
  cast_wT_k<<<dim3(192, 64), 256, 0, stream>>>(d_in[1], WqkvT, flag, DIN, N3);
  cast_wT_k<<<dim3(64, 64), 256, 0, stream>>>(d_in[2], WprojT, flag, DIN, DIN);
  gemm_qkv_k<<<dim3(48, 32), 256, 0, stream>>>(Xb, WqkvT, Qb, Kb, Vb);
  rope_k<<<16384, 256, 0, stream>>>(Qb, Kb);
  transpose_v_k<<<dim3(64, 4, 32), 256, 0, stream>>>(Vb, Vt);
  attn_k<<<dim3(32, 16), 256, 0, stream>>>(Qb, Kb, Vt, Yb);
  gemm_proj_k<<<dim3(16, 32), 256, 0, stream>>>(Yb, WprojT, d_out, flag);
}

// Round 3
// 455.354 us; speedup vs baseline: 2.2449x; 1.0473x over previous
//
#include <hip/hip_runtime.h>

#define DIN 2048
#define NH 16
#define DH 128
#define SEQ 2048
#define BB 2
#define N3 6144
#define MM 4096  // BB*SEQ

typedef __bf16 bf16;
typedef __attribute__((ext_vector_type(8))) __bf16 bf16x8;
typedef __attribute__((ext_vector_type(4))) __bf16 bf16x4;
typedef __attribute__((ext_vector_type(4))) float f32x4;

__device__ __forceinline__ f32x4 mfma16(bf16x8 a, bf16x8 b, f32x4 c) {
  return __builtin_amdgcn_mfma_f32_16x16x32_bf16(a, b, c, 0, 0, 0);
}

__device__ __forceinline__ void async16(const void* g, void* l) {
  __builtin_amdgcn_global_load_lds((const __attribute__((address_space(1))) void*)g,
                                   (__attribute__((address_space(3))) void*)l, 16, 0, 0);
}

// ---------------- dtype sniff ----------------
__global__ void sniff_k(const unsigned short* __restrict__ x, int* __restrict__ flag) {
  __shared__ int cnt;
  if (threadIdx.x == 0) cnt = 0;
  __syncthreads();
  unsigned short u = x[threadIdx.x * 2];
  int e = (u >> 7) & 0xff;
  if (e >= 108 && e <= 140) atomicAdd(&cnt, 1);
  __syncthreads();
  if (threadIdx.x == 0) *flag = (cnt >= 128) ? 1 : 0;
}

// ---------------- casts ----------------
__global__ __launch_bounds__(256) void cast_x_k(const void* __restrict__ in, bf16* __restrict__ out,
                                                const int* __restrict__ flag) {
  size_t i = ((size_t)blockIdx.x * 256 + threadIdx.x) * 8;
  if (*flag) {
    *(bf16x8*)(out + i) = *(const bf16x8*)((const bf16*)in + i);
  } else {
    const float* f = (const float*)in;
    bf16x8 v;
    for (int j = 0; j < 8; j++) v[j] = (bf16)f[i + j];
    *(bf16x8*)(out + i) = v;
  }
}

__global__ __launch_bounds__(256) void cast_wT_k(const void* __restrict__ in, bf16* __restrict__ out,
                                                 const int* __restrict__ flag, int R, int C) {
  __shared__ float t[32][33];
  int c0 = blockIdx.x * 32, r0 = blockIdx.y * 32;
  int tx = threadIdx.x & 31, ty = threadIdx.x >> 5;
  bool isb = *flag != 0;
  for (int j = 0; j < 4; j++) {
    int r = ty + j * 8;
    size_t idx = (size_t)(r0 + r) * C + c0 + tx;
    float v = isb ? (float)((const bf16*)in)[idx] : ((const float*)in)[idx];
    t[r][tx] = v;
  }
  __syncthreads();
  for (int j = 0; j < 4; j++) {
    int c = ty + j * 8;
    out[(size_t)(c0 + c) * R + r0 + tx] = (bf16)t[tx][c];
  }
}

// ---------------- qkv GEMM ----------------
// K is written with per-row 16B-chunk xor swizzle: chunk c of row s stored at c^(s&7),
// so attn's DMA-staged LDS tile reads are bank-conflict-free.
__global__ __launch_bounds__(256) void gemm_qkv_k(const bf16* __restrict__ A, const bf16* __restrict__ BT,
                                                  bf16* __restrict__ Qb, bf16* __restrict__ Kb,
                                                  bf16* __restrict__ Vb) {
  __shared__ __align__(16) bf16 As[128 * 32];
  __shared__ __align__(16) bf16 Bs[128 * 32];
  const int K = DIN;
  int m0 = blockIdx.y * 128, n0 = blockIdx.x * 128;
  int tid = threadIdx.x, w = tid >> 6, l = tid & 63;
  int l15 = l & 15, quad = l >> 4;
  int wm = (w & 1) * 64, wn = (w >> 1) * 64;
  f32x4 zero = {0.f, 0.f, 0.f, 0.f};
  f32x4 acc[4][4];
  for (int i = 0; i < 4; i++)
    for (int j = 0; j < 4; j++) acc[i][j] = zero;
  const bf16* Ag = A + (size_t)(m0 + w * 32 + (l >> 2)) * K + (l & 3) * 8;
  const bf16* Bg = BT + (size_t)(n0 + w * 32 + (l >> 2)) * K + (l & 3) * 8;
  bf16* AsW = As + (w * 32) * 32;
  bf16* BsW = Bs + (w * 32) * 32;
  for (int k0 = 0; k0 < K; k0 += 32) {
    __syncthreads();
    async16(Ag + k0, AsW);
    async16(Ag + k0 + 16 * K, AsW + 16 * 32);
    async16(Bg + k0, BsW);
    async16(Bg + k0 + 16 * K, BsW + 16 * 32);
    __syncthreads();
    bf16x8 af[4], bfv[4];
    for (int i = 0; i < 4; i++) af[i] = *(const bf16x8*)&As[(wm + i * 16 + l15) * 32 + quad * 8];
    for (int j = 0; j < 4; j++) bfv[j] = *(const bf16x8*)&Bs[(wn + j * 16 + l15) * 32 + quad * 8];
    for (int i = 0; i < 4; i++)
      for (int j = 0; j < 4; j++) acc[i][j] = mfma16(af[i], bfv[j], acc[i][j]);
  }
  for (int j = 0; j < 4; j++) {
    int col = n0 + wn + j * 16 + l15;
    int part = col >> 11, cw = col & 2047;
    int h = cw >> 7, d = cw & 127;
    bf16* dst = (part == 0) ? Qb : ((part == 1) ? Kb : Vb);
    for (int i = 0; i < 4; i++) {
      int mrow = m0 + wm + i * 16 + quad * 4;
      for (int r = 0; r < 4; r++) {
        int m = mrow + r;
        int b = m >> 11, s = m & 2047;
        int dd = (part == 1) ? (((((d >> 3) ^ (s & 7)) << 3)) | (d & 7)) : d;
        dst[(((size_t)(b * NH + h)) * SEQ + s) * DH + dd] = (bf16)acc[i][j][r];
      }
    }
  }
}

// ---------------- RoPE; Q gets DH^-0.5 * log2(e) folded in (scores in log2 domain) ----
__global__ __launch_bounds__(256) void rope_k(bf16* __restrict__ Qb, bf16* __restrict__ Kb) {
  int i = blockIdx.x * 256 + threadIdx.x;  // (bh, s, d2): 32*2048*64
  int d2 = i & 63;
  int s = (i >> 6) & 2047;
  int bh = i >> 17;
  int dl = 2 * d2;
  float invf = expf(-9.210340371976184f * (float)dl * (1.0f / 128.0f));
  float ang = (float)s * invf;
  float sn, cs;
  sincosf(ang, &sn, &cs);
  size_t row = ((size_t)bh * SEQ + s) * DH;
  const float scale = 0.08838834764831845f * 1.4426950408889634f;  // DH^-0.5 * log2(e)
  size_t qb = row + dl;
  float q1 = (float)Qb[qb], q2 = (float)Qb[qb + 1];
  Qb[qb] = (bf16)((q1 * cs - q2 * sn) * scale);
  Qb[qb + 1] = (bf16)((q1 * sn + q2 * cs) * scale);
  size_t kb = row + ((((dl >> 3) ^ (s & 7)) << 3) | (dl & 7));
  float k1 = (float)Kb[kb], k2 = (float)Kb[kb + 1];
  Kb[kb] = (bf16)(k1 * cs - k2 * sn);
  Kb[kb + 1] = (bf16)(k1 * sn + k2 * cs);
}

// ---------------- V transpose: (B,H,S,DH) -> (B,H,DH,S), swizzled within 64-col windows
__global__ __launch_bounds__(256) void transpose_v_k(const bf16* __restrict__ V, bf16* __restrict__ Vt) {
  __shared__ float t[32][33];
  int s0 = blockIdx.x * 32, d0 = blockIdx.y * 32;
  int bh = blockIdx.z;
  const bf16* Vp = V + (size_t)bh * SEQ * DH;
  bf16* Vo = Vt + (size_t)bh * DH * SEQ;
  int tx = threadIdx.x & 31, ty = threadIdx.x >> 5;
  for (int j = 0; j < 4; j++)
    t[ty + j * 8][tx] = (float)Vp[(size_t)(s0 + ty + j * 8) * DH + d0 + tx];
  __syncthreads();
  for (int j = 0; j < 4; j++) {
    int dh = d0 + ty + j * 8;
    int s = s0 + tx;
    int sl = s & 63;
    int col = (s & ~63) | ((((sl >> 3) ^ (dh & 7)) << 3) | (sl & 7));
    Vo[(size_t)dh * SEQ + col] = (bf16)t[tx][ty + j * 8];
  }
}

// ---------------- flash attention v3 ----------------
// grid (32 bh, 8 slots); slot handles Q-tiles (15-slot, slot): equal 34 k-iters/block.
// S^T trick: scores computed transposed so softmax is per-lane (col=l15=q), only
// 2 shuffles per reduction. O^T accumulate (col=l15=q) -> scalar alpha rescale.
__global__ __launch_bounds__(256, 1) void attn_k(const bf16* __restrict__ Qb, const bf16* __restrict__ Kb,
                                                 const bf16* __restrict__ Vt, bf16* __restrict__ Yb) {
  __shared__ __align__(16) bf16 Ks[2][64 * 128];
  __shared__ __align__(16) bf16 Vs[2][128 * 64];
  __shared__ __align__(16) bf16 Pl[4][32 * 72];
  int bh = blockIdx.x;
  int slot = blockIdx.y;
  int w = threadIdx.x >> 6, l = threadIdx.x & 63;
  int l15 = l & 15, quad = l >> 4;
  const bf16* Qp = Qb + (size_t)bh * SEQ * DH;
  const bf16* Kp = Kb + (size_t)bh * SEQ * DH;
  const bf16* Vp = Vt + (size_t)bh * DH * SEQ;
  int b = bh >> 4, h = bh & 15;
  f32x4 zero = {0.f, 0.f, 0.f, 0.f};
  bf16* P = &Pl[w][0];

  auto stage = [&](int it, int buf) {
    const char* gk = (const char*)Kp + (size_t)it * 16384 + w * 4096 + l * 16;
    char* lk = (char*)&Ks[buf][0] + w * 4096;
    for (int i = 0; i < 4; i++) async16(gk + i * 1024, lk + i * 1024);
    const char* gv = (const char*)Vp + (size_t)it * 128 + (size_t)(w * 32 + (l >> 3)) * (SEQ * 2) + (l & 7) * 16;
    char* lv = (char*)&Vs[buf][0] + w * 32 * 128;
    for (int i = 0; i < 4; i++) async16(gv + (size_t)i * 8 * (SEQ * 2), lv + i * 1024);
  };

  int tiles[2] = {15 - slot, slot};
  for (int half = 0; half < 2; half++) {
    int tile = tiles[half];
    int q0 = tile * 128;
    int qw = q0 + w * 32;
    bf16x8 qf[2][4];
    for (int rb = 0; rb < 2; rb++)
      for (int kc = 0; kc < 4; kc++)
        qf[rb][kc] = *(const bf16x8*)&Qp[(size_t)(qw + rb * 16 + l15) * DH + kc * 32 + quad * 8];
    f32x4 o[2][8];
    for (int rb = 0; rb < 2; rb++)
      for (int ns = 0; ns < 8; ns++) o[rb][ns] = zero;
    float mprev[2] = {-1e30f, -1e30f}, lsum[2] = {0.f, 0.f};
    int nkt = 2 * tile + 2;

    stage(0, 0);
    __syncthreads();
    for (int it = 0; it < nkt; it++) {
      int buf = it & 1;
      if (it + 1 < nkt) stage(it + 1, buf ^ 1);
      int k0 = it * 64;
      bool act1 = (k0 <= qw + 31);
      bool act0 = (k0 <= qw + 15);
      if (act1) {
        f32x4 st0[4], st1[4];
        for (int ns = 0; ns < 4; ns++) { st0[ns] = zero; st1[ns] = zero; }
        for (int kc = 0; kc < 4; kc++)
          for (int ns = 0; ns < 4; ns++) {
            bf16x8 kf = *(const bf16x8*)&Ks[buf][(ns * 16 + l15) * 128 + (((kc * 4 + quad) ^ (l15 & 7)) << 3)];
            st1[ns] = mfma16(kf, qf[1][kc], st1[ns]);  // S^T: row=k, col=l15=q
            if (act0) st0[ns] = mfma16(kf, qf[0][kc], st0[ns]);
          }
        for (int rb = 0; rb < 2; rb++) {
          if (rb == 0 && !act0) continue;
          f32x4* st = (rb == 0) ? st0 : st1;
          int qq = qw + rb * 16 + l15;
          if (k0 + 63 > qw + rb * 16) {  // diagonal tile: mask k > q
            for (int ns = 0; ns < 4; ns++) {
              int kk = k0 + ns * 16 + quad * 4;
              for (int r = 0; r < 4; r++)
                if (kk + r > qq) st[ns][r] = -1e30f;
            }
          }
          float pm = -1e30f;
          for (int ns = 0; ns < 4; ns++)
            for (int r = 0; r < 4; r++) pm = fmaxf(pm, st[ns][r]);
          pm = fmaxf(pm, __shfl_xor(pm, 16, 64));
          pm = fmaxf(pm, __shfl_xor(pm, 32, 64));
          float mnew = fmaxf(mprev[rb], pm);
          float al = exp2f(mprev[rb] - mnew);
          mprev[rb] = mnew;
          float ps = 0.f;
          for (int ns = 0; ns < 4; ns++)
            for (int r = 0; r < 4; r++) {
              float e = exp2f(st[ns][r] - mnew);
              st[ns][r] = e;
              ps += e;
            }
          ps += __shfl_xor(ps, 16, 64);
          ps += __shfl_xor(ps, 32, 64);
          lsum[rb] = lsum[rb] * al + ps;
          for (int ns = 0; ns < 8; ns++) o[rb][ns] *= al;
          // P^T (C-layout) -> P[q][k] rows: lane holds k=quad*4..+3 contiguous -> b64 writes
          for (int ns = 0; ns < 4; ns++) {
            bf16x4 pk;
            for (int r = 0; r < 4; r++) pk[r] = (bf16)st[ns][r];
            *(bf16x4*)&P[(rb * 16 + l15) * 72 + ns * 16 + quad * 4] = pk;
          }
        }
        asm volatile("s_waitcnt lgkmcnt(0)" ::: "memory");
        bf16x8 pa0[2], pa1[2];
        for (int kc = 0; kc < 2; kc++)
          pa1[kc] = *(const bf16x8*)&P[(16 + l15) * 72 + kc * 32 + quad * 8];
        if (act0)
          for (int kc = 0; kc < 2; kc++)
            pa0[kc] = *(const bf16x8*)&P[l15 * 72 + kc * 32 + quad * 8];
        for (int ns = 0; ns < 8; ns++)
          for (int kc = 0; kc < 2; kc++) {
            bf16x8 vf = *(const bf16x8*)&Vs[buf][(ns * 16 + l15) * 64 + (((kc * 4 + quad) ^ (l15 & 7)) << 3)];
            o[1][ns] = mfma16(vf, pa1[kc], o[1][ns]);  // O^T: col=l15=q
            if (act0) o[0][ns] = mfma16(vf, pa0[kc], o[0][ns]);
          }
      }
      __syncthreads();
    }
    // epilogue: O^T col=l15=q, row=d (within ns); lsum per-lane matches q
    for (int rb = 0; rb < 2; rb++) {
      float inv = 1.0f / lsum[rb];
      int q = qw + rb * 16 + l15;
      size_t base = ((size_t)(b * SEQ + q)) * DIN + h * DH + quad * 4;
      for (int ns = 0; ns < 8; ns++) {
        bf16x4 pk;
        for (int r = 0; r < 4; r++) pk[r] = (bf16)(o[rb][ns][r] * inv);
        *(bf16x4*)&Yb[base + ns * 16] = pk;
      }
    }
  }
}

// ---------------- proj GEMM ----------------
__global__ __launch_bounds__(256) void gemm_proj_k(const bf16* __restrict__ A, const bf16* __restrict__ BT,
                                                   void* __restrict__ out, const int* __restrict__ flag) {
  __shared__ __align__(16) bf16 As[128 * 32];
  __shared__ __align__(16) bf16 Bs[128 * 32];
  const int K = DIN;
  int m0 = blockIdx.y * 128, n0 = blockIdx.x * 128;
  int tid = threadIdx.x, w = tid >> 6, l = tid & 63;
  int l15 = l & 15, quad = l >> 4;
  int wm = (w & 1) * 64, wn = (w >> 1) * 64;
  bool obf = *flag != 0;
  f32x4 zero = {0.f, 0.f, 0.f, 0.f};
  f32x4 acc[4][4];
  for (int i = 0; i < 4; i++)
    for (int j = 0; j < 4; j++) acc[i][j] = zero;
  const bf16* Ag = A + (size_t)(m0 + w * 32 + (l >> 2)) * K + (l & 3) * 8;
  const bf16* Bg = BT + (size_t)(n0 + w * 32 + (l >> 2)) * K + (l & 3) * 8;
  bf16* AsW = As + (w * 32) * 32;
  bf16* BsW = Bs + (w * 32) * 32;
  for (int k0 = 0; k0 < K; k0 += 32) {
    __syncthreads();
    async16(Ag + k0, AsW);
    async16(Ag + k0 + 16 * K, AsW + 16 * 32);
    async16(Bg + k0, BsW);
    async16(Bg + k0 + 16 * K, BsW + 16 * 32);
    __syncthreads();
    bf16x8 af[4], bfv[4];
    for (int i = 0; i < 4; i++) af[i] = *(const bf16x8*)&As[(wm + i * 16 + l15) * 32 + quad * 8];
    for (int j = 0; j < 4; j++) bfv[j] = *(const bf16x8*)&Bs[(wn + j * 16 + l15) * 32 + quad * 8];
    for (int i = 0; i < 4; i++)
      for (int j = 0; j < 4; j++) acc[i][j] = mfma16(af[i], bfv[j], acc[i][j]);
  }
  for (int j = 0; j < 4; j++) {
    int col = n0 + wn + j * 16 + l15;
    for (int i = 0; i < 4; i++) {
      int mrow = m0 + wm + i * 16 + quad * 4;
      for (int r = 0; r < 4; r++) {
        size_t idx = (size_t)(mrow + r) * DIN + col;
        float v = acc[i][j][r];
        if (obf)
          ((bf16*)out)[idx] = (bf16)v;
        else
          ((float*)out)[idx] = v;
      }
    }
  }
}

extern "C" void kernel_launch(void* const* d_in, const int* in_sizes, int n_in,
                              void* d_out, int out_size, void* d_ws, size_t ws_size,
                              hipStream_t stream) {
  char* ws = (char*)d_ws;
  int* flag = (int*)ws;
  bf16* Xb = (bf16*)(ws + 256);                                  // 16 MiB, aliased with Yb
  bf16* WqkvT = (bf16*)(ws + 256 + 16777216);                    // 24 MiB
  bf16* WprojT = (bf16*)(ws + 256 + 16777216 + 25165824);        // 8 MiB
  bf16* Qb = (bf16*)(ws + 256 + 16777216 + 25165824 + 8388608);  // 16 MiB each
  bf16* Kb = Qb + (size_t)MM * DIN;
  bf16* Vb = Kb + (size_t)MM * DIN;
  bf16* Vt = Vb + (size_t)MM * DIN;
  bf16* Yb = Xb;  // Xb dead after gemm_qkv

  sniff_k<<<1, 256, 0, stream>>>((const unsigned short*)d_in[0], flag);
  cast_x_k<<<4096, 256, 0, stream>>>(d_in[0], Xb, flag);
  cast_wT_k<<<dim3(192, 64), 256, 0, stream>>>(d_in[1], WqkvT, flag, DIN, N3);
  cast_wT_k<<<dim3(64, 64), 256, 0, stream>>>(d_in[2], WprojT, flag, DIN, DIN);
  gemm_qkv_k<<<dim3(48, 32), 256, 0, stream>>>(Xb, WqkvT, Qb, Kb, Vb);
  rope_k<<<16384, 256, 0, stream>>>(Qb, Kb);
  transpose_v_k<<<dim3(64, 4, 32), 256, 0, stream>>>(Vb, Vt);
  attn_k<<<dim3(32, 8), 256, 0, stream>>>(Qb, Kb, Vt, Yb);
  gemm_proj_k<<<dim3(16, 32), 256, 0, stream>>>(Yb, WprojT, d_out, flag);
}

// Round 4
// 415.214 us; speedup vs baseline: 2.4619x; 1.0967x over previous
//
#include <hip/hip_runtime.h>

#define DIN 2048
#define NH 16
#define DH 128
#define SEQ 2048
#define BB 2
#define N3 6144
#define MM 4096  // BB*SEQ

typedef __bf16 bf16;
typedef __attribute__((ext_vector_type(8))) __bf16 bf16x8;
typedef __attribute__((ext_vector_type(4))) __bf16 bf16x4;
typedef __attribute__((ext_vector_type(4))) float f32x4;

__device__ __forceinline__ f32x4 mfma16(bf16x8 a, bf16x8 b, f32x4 c) {
  return __builtin_amdgcn_mfma_f32_16x16x32_bf16(a, b, c, 0, 0, 0);
}

__device__ __forceinline__ void async16(const void* g, void* l) {
  __builtin_amdgcn_global_load_lds((const __attribute__((address_space(1))) void*)g,
                                   (__attribute__((address_space(3))) void*)l, 16, 0, 0);
}

// ---------------- dtype sniff ----------------
__global__ void sniff_k(const unsigned short* __restrict__ x, int* __restrict__ flag) {
  __shared__ int cnt;
  if (threadIdx.x == 0) cnt = 0;
  __syncthreads();
  unsigned short u = x[threadIdx.x * 2];
  int e = (u >> 7) & 0xff;
  if (e >= 108 && e <= 140) atomicAdd(&cnt, 1);
  __syncthreads();
  if (threadIdx.x == 0) *flag = (cnt >= 128) ? 1 : 0;
}

// ---------------- casts ----------------
__global__ __launch_bounds__(256) void cast_x_k(const void* __restrict__ in, bf16* __restrict__ out,
                                                const int* __restrict__ flag) {
  size_t i = ((size_t)blockIdx.x * 256 + threadIdx.x) * 8;
  if (*flag) {
    *(bf16x8*)(out + i) = *(const bf16x8*)((const bf16*)in + i);
  } else {
    const float* f = (const float*)in;
    bf16x8 v;
    for (int j = 0; j < 8; j++) v[j] = (bf16)f[i + j];
    *(bf16x8*)(out + i) = v;
  }
}

__global__ __launch_bounds__(256) void cast_wT_k(const void* __restrict__ in, bf16* __restrict__ out,
                                                 const int* __restrict__ flag, int R, int C) {
  __shared__ float t[32][33];
  int c0 = blockIdx.x * 32, r0 = blockIdx.y * 32;
  int tx = threadIdx.x & 31, ty = threadIdx.x >> 5;
  bool isb = *flag != 0;
  for (int j = 0; j < 4; j++) {
    int r = ty + j * 8;
    size_t idx = (size_t)(r0 + r) * C + c0 + tx;
    float v = isb ? (float)((const bf16*)in)[idx] : ((const float*)in)[idx];
    t[r][tx] = v;
  }
  __syncthreads();
  for (int j = 0; j < 4; j++) {
    int c = ty + j * 8;
    out[(size_t)(c0 + c) * R + r0 + tx] = (bf16)t[tx][c];
  }
}

// ---------------- qkv GEMM ----------------
// K is written with per-row 16B-chunk xor swizzle: chunk c of row s stored at c^(s&7),
// so attn's DMA-staged LDS tile reads are bank-conflict-free.
__global__ __launch_bounds__(256) void gemm_qkv_k(const bf16* __restrict__ A, const bf16* __restrict__ BT,
                                                  bf16* __restrict__ Qb, bf16* __restrict__ Kb,
                                                  bf16* __restrict__ Vb) {
  __shared__ __align__(16) bf16 As[128 * 32];
  __shared__ __align__(16) bf16 Bs[128 * 32];
  const int K = DIN;
  int m0 = blockIdx.y * 128, n0 = blockIdx.x * 128;
  int tid = threadIdx.x, w = tid >> 6, l = tid & 63;
  int l15 = l & 15, quad = l >> 4;
  int wm = (w & 1) * 64, wn = (w >> 1) * 64;
  f32x4 zero = {0.f, 0.f, 0.f, 0.f};
  f32x4 acc[4][4];
  for (int i = 0; i < 4; i++)
    for (int j = 0; j < 4; j++) acc[i][j] = zero;
  const bf16* Ag = A + (size_t)(m0 + w * 32 + (l >> 2)) * K + (l & 3) * 8;
  const bf16* Bg = BT + (size_t)(n0 + w * 32 + (l >> 2)) * K + (l & 3) * 8;
  bf16* AsW = As + (w * 32) * 32;
  bf16* BsW = Bs + (w * 32) * 32;
  for (int k0 = 0; k0 < K; k0 += 32) {
    __syncthreads();
    async16(Ag + k0, AsW);
    async16(Ag + k0 + 16 * K, AsW + 16 * 32);
    async16(Bg + k0, BsW);
    async16(Bg + k0 + 16 * K, BsW + 16 * 32);
    __syncthreads();
    bf16x8 af[4], bfv[4];
    for (int i = 0; i < 4; i++) af[i] = *(const bf16x8*)&As[(wm + i * 16 + l15) * 32 + quad * 8];
    for (int j = 0; j < 4; j++) bfv[j] = *(const bf16x8*)&Bs[(wn + j * 16 + l15) * 32 + quad * 8];
    for (int i = 0; i < 4; i++)
      for (int j = 0; j < 4; j++) acc[i][j] = mfma16(af[i], bfv[j], acc[i][j]);
  }
  for (int j = 0; j < 4; j++) {
    int col = n0 + wn + j * 16 + l15;
    int part = col >> 11, cw = col & 2047;
    int h = cw >> 7, d = cw & 127;
    bf16* dst = (part == 0) ? Qb : ((part == 1) ? Kb : Vb);
    for (int i = 0; i < 4; i++) {
      int mrow = m0 + wm + i * 16 + quad * 4;
      for (int r = 0; r < 4; r++) {
        int m = mrow + r;
        int b = m >> 11, s = m & 2047;
        int dd = (part == 1) ? (((((d >> 3) ^ (s & 7)) << 3)) | (d & 7)) : d;
        dst[(((size_t)(b * NH + h)) * SEQ + s) * DH + dd] = (bf16)acc[i][j][r];
      }
    }
  }
}

// ---------------- RoPE; Q gets DH^-0.5 * log2(e) folded in (scores in log2 domain) ----
__global__ __launch_bounds__(256) void rope_k(bf16* __restrict__ Qb, bf16* __restrict__ Kb) {
  int i = blockIdx.x * 256 + threadIdx.x;  // (bh, s, d2): 32*2048*64
  int d2 = i & 63;
  int s = (i >> 6) & 2047;
  int bh = i >> 17;
  int dl = 2 * d2;
  float invf = expf(-9.210340371976184f * (float)dl * (1.0f / 128.0f));
  float ang = (float)s * invf;
  float sn, cs;
  sincosf(ang, &sn, &cs);
  size_t row = ((size_t)bh * SEQ + s) * DH;
  const float scale = 0.08838834764831845f * 1.4426950408889634f;  // DH^-0.5 * log2(e)
  size_t qb = row + dl;
  float q1 = (float)Qb[qb], q2 = (float)Qb[qb + 1];
  Qb[qb] = (bf16)((q1 * cs - q2 * sn) * scale);
  Qb[qb + 1] = (bf16)((q1 * sn + q2 * cs) * scale);
  size_t kb = row + ((((dl >> 3) ^ (s & 7)) << 3) | (dl & 7));
  float k1 = (float)Kb[kb], k2 = (float)Kb[kb + 1];
  Kb[kb] = (bf16)(k1 * cs - k2 * sn);
  Kb[kb + 1] = (bf16)(k1 * sn + k2 * cs);
}

// ---------------- V transpose: (B,H,S,DH) -> (B,H,DH,S), swizzled within 64-col windows
__global__ __launch_bounds__(256) void transpose_v_k(const bf16* __restrict__ V, bf16* __restrict__ Vt) {
  __shared__ float t[32][33];
  int s0 = blockIdx.x * 32, d0 = blockIdx.y * 32;
  int bh = blockIdx.z;
  const bf16* Vp = V + (size_t)bh * SEQ * DH;
  bf16* Vo = Vt + (size_t)bh * DH * SEQ;
  int tx = threadIdx.x & 31, ty = threadIdx.x >> 5;
  for (int j = 0; j < 4; j++)
    t[ty + j * 8][tx] = (float)Vp[(size_t)(s0 + ty + j * 8) * DH + d0 + tx];
  __syncthreads();
  for (int j = 0; j < 4; j++) {
    int dh = d0 + ty + j * 8;
    int s = s0 + tx;
    int sl = s & 63;
    int col = (s & ~63) | ((((sl >> 3) ^ (dh & 7)) << 3) | (sl & 7));
    Vo[(size_t)dh * SEQ + col] = (bf16)t[tx][ty + j * 8];
  }
}

// ---------------- flash attention v4 ----------------
// Q-tile 64 (4 waves x 16 q-rows), K-tile 64 double-buffered; 73.5 KB LDS ->
// 2 blocks/CU = 2 waves/SIMD so softmax chains of one wave hide under the
// other's MFMA phase. grid (32 bh, 16 slots), slot does Q-tiles (31-slot, slot)
// = exactly 33 k-iters per block.
__global__ __launch_bounds__(256, 2) void attn_k(const bf16* __restrict__ Qb, const bf16* __restrict__ Kb,
                                                 const bf16* __restrict__ Vt, bf16* __restrict__ Yb) {
  __shared__ __align__(16) bf16 Ks[2][64 * 128];
  __shared__ __align__(16) bf16 Vs[2][128 * 64];
  __shared__ __align__(16) bf16 Pl[4][16 * 76];
  int bh = blockIdx.x;
  int slot = blockIdx.y;
  int w = threadIdx.x >> 6, l = threadIdx.x & 63;
  int l15 = l & 15, quad = l >> 4;
  const bf16* Qp = Qb + (size_t)bh * SEQ * DH;
  const bf16* Kp = Kb + (size_t)bh * SEQ * DH;
  const bf16* Vp = Vt + (size_t)bh * DH * SEQ;
  int b = bh >> 4, h = bh & 15;
  f32x4 zero = {0.f, 0.f, 0.f, 0.f};
  bf16* P = &Pl[w][0];

  auto stage = [&](int it, int buf) {
    const char* gk = (const char*)Kp + (size_t)it * 16384 + w * 4096 + l * 16;
    char* lk = (char*)&Ks[buf][0] + w * 4096;
    for (int i = 0; i < 4; i++) async16(gk + i * 1024, lk + i * 1024);
    const char* gv = (const char*)Vp + (size_t)it * 128 + (size_t)(w * 32 + (l >> 3)) * (SEQ * 2) + (l & 7) * 16;
    char* lv = (char*)&Vs[buf][0] + w * 32 * 128;
    for (int i = 0; i < 4; i++) async16(gv + (size_t)i * 8 * (SEQ * 2), lv + i * 1024);
  };

  int tiles[2] = {31 - slot, slot};
  for (int half = 0; half < 2; half++) {
    int tile = tiles[half];
    int qw = tile * 64 + w * 16;  // this wave's 16 q rows
    bf16x8 qf[4];
    for (int kc = 0; kc < 4; kc++)
      qf[kc] = *(const bf16x8*)&Qp[(size_t)(qw + l15) * DH + kc * 32 + quad * 8];
    f32x4 o[8];
    for (int ns = 0; ns < 8; ns++) o[ns] = zero;
    float mprev = -1e30f, lsum = 0.f;
    int nkt = tile + 1;

    stage(0, 0);
    __syncthreads();
    for (int it = 0; it < nkt; it++) {
      int buf = it & 1;
      if (it + 1 < nkt) stage(it + 1, buf ^ 1);
      int k0 = it * 64;
      // S^T = K(row) x Q(col=l15=q)
      f32x4 st[4];
      for (int ns = 0; ns < 4; ns++) st[ns] = zero;
      for (int kc = 0; kc < 4; kc++)
        for (int ns = 0; ns < 4; ns++) {
          bf16x8 kf = *(const bf16x8*)&Ks[buf][(ns * 16 + l15) * 128 + (((kc * 4 + quad) ^ (l15 & 7)) << 3)];
          st[ns] = mfma16(kf, qf[kc], st[ns]);
        }
      int qq = qw + l15;
      if (k0 + 63 > qw) {  // diagonal tile: mask k > q
        for (int ns = 0; ns < 4; ns++) {
          int kk = k0 + ns * 16 + quad * 4;
          for (int r = 0; r < 4; r++)
            if (kk + r > qq) st[ns][r] = -1e30f;
        }
      }
      float pm = -1e30f;
      for (int ns = 0; ns < 4; ns++)
        for (int r = 0; r < 4; r++) pm = fmaxf(pm, st[ns][r]);
      pm = fmaxf(pm, __shfl_xor(pm, 16, 64));
      pm = fmaxf(pm, __shfl_xor(pm, 32, 64));
      float mnew = fmaxf(mprev, pm);
      float al = exp2f(mprev - mnew);
      mprev = mnew;
      float ps = 0.f;
      for (int ns = 0; ns < 4; ns++)
        for (int r = 0; r < 4; r++) {
          float e = exp2f(st[ns][r] - mnew);
          st[ns][r] = e;
          ps += e;
        }
      ps += __shfl_xor(ps, 16, 64);
      ps += __shfl_xor(ps, 32, 64);
      lsum = lsum * al + ps;
      for (int ns = 0; ns < 8; ns++) o[ns] *= al;
      // P^T (C-layout) -> P[q][k] rows: lane holds k=quad*4..+3 contiguous -> b64 writes
      for (int ns = 0; ns < 4; ns++) {
        bf16x4 pk;
        for (int r = 0; r < 4; r++) pk[r] = (bf16)st[ns][r];
        *(bf16x4*)&P[l15 * 76 + ns * 16 + quad * 4] = pk;
      }
      asm volatile("s_waitcnt lgkmcnt(0)" ::: "memory");
      bf16x8 pa[2];
      for (int kc = 0; kc < 2; kc++)
        pa[kc] = *(const bf16x8*)&P[l15 * 76 + kc * 32 + quad * 8];
      for (int ns = 0; ns < 8; ns++)
        for (int kc = 0; kc < 2; kc++) {
          bf16x8 vf = *(const bf16x8*)&Vs[buf][(ns * 16 + l15) * 64 + (((kc * 4 + quad) ^ (l15 & 7)) << 3)];
          o[ns] = mfma16(vf, pa[kc], o[ns]);  // O^T: col=l15=q
        }
      __syncthreads();
    }
    // epilogue: O^T col=l15=q, row(within ns)=quad*4+r -> d = ns*16+quad*4+r
    float inv = 1.0f / lsum;
    int q = qw + l15;
    size_t base = ((size_t)(b * SEQ + q)) * DIN + h * DH + quad * 4;
    for (int ns = 0; ns < 8; ns++) {
      bf16x4 pk;
      for (int r = 0; r < 4; r++) pk[r] = (bf16)(o[ns][r] * inv);
      *(bf16x4*)&Yb[base + ns * 16] = pk;
    }
  }
}

// ---------------- proj GEMM ----------------
__global__ __launch_bounds__(256) void gemm_proj_k(const bf16* __restrict__ A, const bf16* __restrict__ BT,
                                                   void* __restrict__ out, const int* __restrict__ flag) {
  __shared__ __align__(16) bf16 As[128 * 32];
  __shared__ __align__(16) bf16 Bs[128 * 32];
  const int K = DIN;
  int m0 = blockIdx.y * 128, n0 = blockIdx.x * 128;
  int tid = threadIdx.x, w = tid >> 6, l = tid & 63;
  int l15 = l & 15, quad = l >> 4;
  int wm = (w & 1) * 64, wn = (w >> 1) * 64;
  bool obf = *flag != 0;
  f32x4 zero = {0.f, 0.f, 0.f, 0.f};
  f32x4 acc[4][4];
  for (int i = 0; i < 4; i++)
    for (int j = 0; j < 4; j++) acc[i][j] = zero;
  const bf16* Ag = A + (size_t)(m0 + w * 32 + (l >> 2)) * K + (l & 3) * 8;
  const bf16* Bg = BT + (size_t)(n0 + w * 32 + (l >> 2)) * K + (l & 3) * 8;
  bf16* AsW = As + (w * 32) * 32;
  bf16* BsW = Bs + (w * 32) * 32;
  for (int k0 = 0; k0 < K; k0 += 32) {
    __syncthreads();
    async16(Ag + k0, AsW);
    async16(Ag + k0 + 16 * K, AsW + 16 * 32);
    async16(Bg + k0, BsW);
    async16(Bg + k0 + 16 * K, BsW + 16 * 32);
    __syncthreads();
    bf16x8 af[4], bfv[4];
    for (int i = 0; i < 4; i++) af[i] = *(const bf16x8*)&As[(wm + i * 16 + l15) * 32 + quad * 8];
    for (int j = 0; j < 4; j++) bfv[j] = *(const bf16x8*)&Bs[(wn + j * 16 + l15) * 32 + quad * 8];
    for (int i = 0; i < 4; i++)
      for (int j = 0; j < 4; j++) acc[i][j] = mfma16(af[i], bfv[j], acc[i][j]);
  }
  for (int j = 0; j < 4; j++) {
    int col = n0 + wn + j * 16 + l15;
    for (int i = 0; i < 4; i++) {
      int mrow = m0 + wm + i * 16 + quad * 4;
      for (int r = 0; r < 4; r++) {
        size_t idx = (size_t)(mrow + r) * DIN + col;
        float v = acc[i][j][r];
        if (obf)
          ((bf16*)out)[idx] = (bf16)v;
        else
          ((float*)out)[idx] = v;
      }
    }
  }
}

extern "C" void kernel_launch(void* const* d_in, const int* in_sizes, int n_in,
                              void* d_out, int out_size, void* d_ws, size_t ws_size,
                              hipStream_t stream) {
  char* ws = (char*)d_ws;
  int* flag = (int*)ws;
  bf16* Xb = (bf16*)(ws + 256);                                  // 16 MiB, aliased with Yb
  bf16* WqkvT = (bf16*)(ws + 256 + 16777216);                    // 24 MiB
  bf16* WprojT = (bf16*)(ws + 256 + 16777216 + 25165824);        // 8 MiB
  bf16* Qb = (bf16*)(ws + 256 + 16777216 + 25165824 + 8388608);  // 16 MiB each
  bf16* Kb = Qb + (size_t)MM * DIN;
  bf16* Vb = Kb + (size_t)MM * DIN;
  bf16* Vt = Vb + (size_t)MM * DIN;
  bf16* Yb = Xb;  // Xb dead after gemm_qkv

  sniff_k<<<1, 256, 0, stream>>>((const unsigned short*)d_in[0], flag);
  cast_x_k<<<4096, 256, 0, stream>>>(d_in[0], Xb, flag);
  cast_wT_k<<<dim3(192, 64), 256, 0, stream>>>(d_in[1], WqkvT, flag, DIN, N3);
  cast_wT_k<<<dim3(64, 64), 256, 0, stream>>>(d_in[2], WprojT, flag, DIN, DIN);
  gemm_qkv_k<<<dim3(48, 32), 256, 0, stream>>>(Xb, WqkvT, Qb, Kb, Vb);
  rope_k<<<16384, 256, 0, stream>>>(Qb, Kb);
  transpose_v_k<<<dim3(64, 4, 32), 256, 0, stream>>>(Vb, Vt);
  attn_k<<<dim3(32, 16), 256, 0, stream>>>(Qb, Kb, Vt, Yb);
  gemm_proj_k<<<dim3(16, 32), 256, 0, stream>>>(Yb, WprojT, d_out, flag);
}

// Round 5
// 397.599 us; speedup vs baseline: 2.5710x; 1.0443x over previous
//
#include <hip/hip_runtime.h>

#define DIN 2048
#define NH 16
#define DH 128
#define SEQ 2048
#define BB 2
#define N3 6144
#define MM 4096  // BB*SEQ

typedef __bf16 bf16;
typedef __attribute__((ext_vector_type(8))) __bf16 bf16x8;
typedef __attribute__((ext_vector_type(4))) __bf16 bf16x4;
typedef __attribute__((ext_vector_type(4))) float f32x4;

__device__ __forceinline__ f32x4 mfma16(bf16x8 a, bf16x8 b, f32x4 c) {
  return __builtin_amdgcn_mfma_f32_16x16x32_bf16(a, b, c, 0, 0, 0);
}

__device__ __forceinline__ void async16(const void* g, void* l) {
  __builtin_amdgcn_global_load_lds((const __attribute__((address_space(1))) void*)g,
                                   (__attribute__((address_space(3))) void*)l, 16, 0, 0);
}

// ---------------- dtype sniff ----------------
__global__ void sniff_k(const unsigned short* __restrict__ x, int* __restrict__ flag) {
  __shared__ int cnt;
  if (threadIdx.x == 0) cnt = 0;
  __syncthreads();
  unsigned short u = x[threadIdx.x * 2];
  int e = (u >> 7) & 0xff;
  if (e >= 108 && e <= 140) atomicAdd(&cnt, 1);
  __syncthreads();
  if (threadIdx.x == 0) *flag = (cnt >= 128) ? 1 : 0;
}

// ---------------- casts ----------------
__global__ __launch_bounds__(256) void cast_x_k(const void* __restrict__ in, bf16* __restrict__ out,
                                                const int* __restrict__ flag) {
  size_t i = ((size_t)blockIdx.x * 256 + threadIdx.x) * 8;
  if (*flag) {
    *(bf16x8*)(out + i) = *(const bf16x8*)((const bf16*)in + i);
  } else {
    const float* f = (const float*)in;
    bf16x8 v;
    for (int j = 0; j < 8; j++) v[j] = (bf16)f[i + j];
    *(bf16x8*)(out + i) = v;
  }
}

__global__ __launch_bounds__(256) void cast_wT_k(const void* __restrict__ in, bf16* __restrict__ out,
                                                 const int* __restrict__ flag, int R, int C) {
  __shared__ float t[32][33];
  int c0 = blockIdx.x * 32, r0 = blockIdx.y * 32;
  int tx = threadIdx.x & 31, ty = threadIdx.x >> 5;
  bool isb = *flag != 0;
  for (int j = 0; j < 4; j++) {
    int r = ty + j * 8;
    size_t idx = (size_t)(r0 + r) * C + c0 + tx;
    float v = isb ? (float)((const bf16*)in)[idx] : ((const float*)in)[idx];
    t[r][tx] = v;
  }
  __syncthreads();
  for (int j = 0; j < 4; j++) {
    int c = ty + j * 8;
    out[(size_t)(c0 + c) * R + r0 + tx] = (bf16)t[tx][c];
  }
}

// ---------------- qkv GEMM (BK=64, xor-swizzled LDS chunks) ----------------
// LDS tiles 128x64 bf16 (128 B/row = 8 x 16B chunks). Staging DMA places global
// chunk (c ^ (row&7)) at physical chunk c, so fragment b128 reads land 2 lanes/
// bank-group (free). K output rows additionally carry the global 16B-chunk xor
// swizzle (c^(s&7)) consumed by attn's DMA staging.
__global__ __launch_bounds__(256) void gemm_qkv_k(const bf16* __restrict__ A, const bf16* __restrict__ BT,
                                                  bf16* __restrict__ Qb, bf16* __restrict__ Kb,
                                                  bf16* __restrict__ Vb) {
  __shared__ __align__(16) bf16 As[128 * 64];
  __shared__ __align__(16) bf16 Bs[128 * 64];
  const int K = DIN;
  int m0 = blockIdx.y * 128, n0 = blockIdx.x * 128;
  int tid = threadIdx.x, w = tid >> 6, l = tid & 63;
  int l15 = l & 15, quad = l >> 4;
  int wm = (w & 1) * 64, wn = (w >> 1) * 64;
  f32x4 zero = {0.f, 0.f, 0.f, 0.f};
  f32x4 acc[4][4];
  for (int i = 0; i < 4; i++)
    for (int j = 0; j < 4; j++) acc[i][j] = zero;
  int gch = (l & 7) ^ (l >> 3);  // swizzled source chunk for this lane
  const bf16* Ag = A + (size_t)(m0 + w * 32 + (l >> 3)) * K + gch * 8;
  const bf16* Bg = BT + (size_t)(n0 + w * 32 + (l >> 3)) * K + gch * 8;
  bf16* AsW = As + w * 2048;  // wave stages rows w*32..+31 (4 KB)
  bf16* BsW = Bs + w * 2048;
  for (int k0 = 0; k0 < K; k0 += 64) {
    __syncthreads();
    for (int j = 0; j < 4; j++) async16(Ag + k0 + (size_t)j * 8 * K, AsW + j * 512);
    for (int j = 0; j < 4; j++) async16(Bg + k0 + (size_t)j * 8 * K, BsW + j * 512);
    __syncthreads();
    for (int kk = 0; kk < 2; kk++) {
      bf16x8 af[4], bfv[4];
      for (int i = 0; i < 4; i++)
        af[i] = *(const bf16x8*)&As[(wm + i * 16 + l15) * 64 + (((kk * 4 + quad) ^ (l15 & 7)) << 3)];
      for (int j = 0; j < 4; j++)
        bfv[j] = *(const bf16x8*)&Bs[(wn + j * 16 + l15) * 64 + (((kk * 4 + quad) ^ (l15 & 7)) << 3)];
      for (int i = 0; i < 4; i++)
        for (int j = 0; j < 4; j++) acc[i][j] = mfma16(af[i], bfv[j], acc[i][j]);
    }
  }
  for (int j = 0; j < 4; j++) {
    int col = n0 + wn + j * 16 + l15;
    int part = col >> 11, cw = col & 2047;
    int h = cw >> 7, d = cw & 127;
    bf16* dst = (part == 0) ? Qb : ((part == 1) ? Kb : Vb);
    for (int i = 0; i < 4; i++) {
      int mrow = m0 + wm + i * 16 + quad * 4;
      for (int r = 0; r < 4; r++) {
        int m = mrow + r;
        int b = m >> 11, s = m & 2047;
        int dd = (part == 1) ? (((((d >> 3) ^ (s & 7)) << 3)) | (d & 7)) : d;
        dst[(((size_t)(b * NH + h)) * SEQ + s) * DH + dd] = (bf16)acc[i][j][r];
      }
    }
  }
}

// ---------------- RoPE; Q gets DH^-0.5 * log2(e) folded in (scores in log2 domain) ----
__global__ __launch_bounds__(256) void rope_k(bf16* __restrict__ Qb, bf16* __restrict__ Kb) {
  int i = blockIdx.x * 256 + threadIdx.x;  // (bh, s, d2): 32*2048*64
  int d2 = i & 63;
  int s = (i >> 6) & 2047;
  int bh = i >> 17;
  int dl = 2 * d2;
  float invf = expf(-9.210340371976184f * (float)dl * (1.0f / 128.0f));
  float ang = (float)s * invf;
  float sn, cs;
  sincosf(ang, &sn, &cs);
  size_t row = ((size_t)bh * SEQ + s) * DH;
  const float scale = 0.08838834764831845f * 1.4426950408889634f;  // DH^-0.5 * log2(e)
  size_t qb = row + dl;
  float q1 = (float)Qb[qb], q2 = (float)Qb[qb + 1];
  Qb[qb] = (bf16)((q1 * cs - q2 * sn) * scale);
  Qb[qb + 1] = (bf16)((q1 * sn + q2 * cs) * scale);
  size_t kb = row + ((((dl >> 3) ^ (s & 7)) << 3) | (dl & 7));
  float k1 = (float)Kb[kb], k2 = (float)Kb[kb + 1];
  Kb[kb] = (bf16)(k1 * cs - k2 * sn);
  Kb[kb + 1] = (bf16)(k1 * sn + k2 * cs);
}

// ---------------- V transpose: (B,H,S,DH) -> (B,H,DH,S), swizzled within 64-col windows
__global__ __launch_bounds__(256) void transpose_v_k(const bf16* __restrict__ V, bf16* __restrict__ Vt) {
  __shared__ float t[32][33];
  int s0 = blockIdx.x * 32, d0 = blockIdx.y * 32;
  int bh = blockIdx.z;
  const bf16* Vp = V + (size_t)bh * SEQ * DH;
  bf16* Vo = Vt + (size_t)bh * DH * SEQ;
  int tx = threadIdx.x & 31, ty = threadIdx.x >> 5;
  for (int j = 0; j < 4; j++)
    t[ty + j * 8][tx] = (float)Vp[(size_t)(s0 + ty + j * 8) * DH + d0 + tx];
  __syncthreads();
  for (int j = 0; j < 4; j++) {
    int dh = d0 + ty + j * 8;
    int s = s0 + tx;
    int sl = s & 63;
    int col = (s & ~63) | ((((sl >> 3) ^ (dh & 7)) << 3) | (sl & 7));
    Vo[(size_t)dh * SEQ + col] = (bf16)t[tx][ty + j * 8];
  }
}

// ---------------- flash attention v4 ----------------
// Q-tile 64 (4 waves x 16 q-rows), K-tile 64 double-buffered; 73.5 KB LDS ->
// 2 blocks/CU = 2 waves/SIMD. grid (32 bh, 16 slots), slot does Q-tiles
// (31-slot, slot) = exactly 33 k-iters per block.
__global__ __launch_bounds__(256, 2) void attn_k(const bf16* __restrict__ Qb, const bf16* __restrict__ Kb,
                                                 const bf16* __restrict__ Vt, bf16* __restrict__ Yb) {
  __shared__ __align__(16) bf16 Ks[2][64 * 128];
  __shared__ __align__(16) bf16 Vs[2][128 * 64];
  __shared__ __align__(16) bf16 Pl[4][16 * 76];
  int bh = blockIdx.x;
  int slot = blockIdx.y;
  int w = threadIdx.x >> 6, l = threadIdx.x & 63;
  int l15 = l & 15, quad = l >> 4;
  const bf16* Qp = Qb + (size_t)bh * SEQ * DH;
  const bf16* Kp = Kb + (size_t)bh * SEQ * DH;
  const bf16* Vp = Vt + (size_t)bh * DH * SEQ;
  int b = bh >> 4, h = bh & 15;
  f32x4 zero = {0.f, 0.f, 0.f, 0.f};
  bf16* P = &Pl[w][0];

  auto stage = [&](int it, int buf) {
    const char* gk = (const char*)Kp + (size_t)it * 16384 + w * 4096 + l * 16;
    char* lk = (char*)&Ks[buf][0] + w * 4096;
    for (int i = 0; i < 4; i++) async16(gk + i * 1024, lk + i * 1024);
    const char* gv = (const char*)Vp + (size_t)it * 128 + (size_t)(w * 32 + (l >> 3)) * (SEQ * 2) + (l & 7) * 16;
    char* lv = (char*)&Vs[buf][0] + w * 32 * 128;
    for (int i = 0; i < 4; i++) async16(gv + (size_t)i * 8 * (SEQ * 2), lv + i * 1024);
  };

  int tiles[2] = {31 - slot, slot};
  for (int half = 0; half < 2; half++) {
    int tile = tiles[half];
    int qw = tile * 64 + w * 16;  // this wave's 16 q rows
    bf16x8 qf[4];
    for (int kc = 0; kc < 4; kc++)
      qf[kc] = *(const bf16x8*)&Qp[(size_t)(qw + l15) * DH + kc * 32 + quad * 8];
    f32x4 o[8];
    for (int ns = 0; ns < 8; ns++) o[ns] = zero;
    float mprev = -1e30f, lsum = 0.f;
    int nkt = tile + 1;

    stage(0, 0);
    __syncthreads();
    for (int it = 0; it < nkt; it++) {
      int buf = it & 1;
      if (it + 1 < nkt) stage(it + 1, buf ^ 1);
      int k0 = it * 64;
      // S^T = K(row) x Q(col=l15=q)
      f32x4 st[4];
      for (int ns = 0; ns < 4; ns++) st[ns] = zero;
      for (int kc = 0; kc < 4; kc++)
        for (int ns = 0; ns < 4; ns++) {
          bf16x8 kf = *(const bf16x8*)&Ks[buf][(ns * 16 + l15) * 128 + (((kc * 4 + quad) ^ (l15 & 7)) << 3)];
          st[ns] = mfma16(kf, qf[kc], st[ns]);
        }
      int qq = qw + l15;
      if (k0 + 63 > qw) {  // diagonal tile: mask k > q
        for (int ns = 0; ns < 4; ns++) {
          int kk = k0 + ns * 16 + quad * 4;
          for (int r = 0; r < 4; r++)
            if (kk + r > qq) st[ns][r] = -1e30f;
        }
      }
      float pm = -1e30f;
      for (int ns = 0; ns < 4; ns++)
        for (int r = 0; r < 4; r++) pm = fmaxf(pm, st[ns][r]);
      pm = fmaxf(pm, __shfl_xor(pm, 16, 64));
      pm = fmaxf(pm, __shfl_xor(pm, 32, 64));
      float mnew = fmaxf(mprev, pm);
      float al = exp2f(mprev - mnew);
      mprev = mnew;
      float ps = 0.f;
      for (int ns = 0; ns < 4; ns++)
        for (int r = 0; r < 4; r++) {
          float e = exp2f(st[ns][r] - mnew);
          st[ns][r] = e;
          ps += e;
        }
      ps += __shfl_xor(ps, 16, 64);
      ps += __shfl_xor(ps, 32, 64);
      lsum = lsum * al + ps;
      for (int ns = 0; ns < 8; ns++) o[ns] *= al;
      // P^T (C-layout) -> P[q][k] rows: lane holds k=quad*4..+3 contiguous -> b64 writes
      for (int ns = 0; ns < 4; ns++) {
        bf16x4 pk;
        for (int r = 0; r < 4; r++) pk[r] = (bf16)st[ns][r];
        *(bf16x4*)&P[l15 * 76 + ns * 16 + quad * 4] = pk;
      }
      asm volatile("s_waitcnt lgkmcnt(0)" ::: "memory");
      bf16x8 pa[2];
      for (int kc = 0; kc < 2; kc++)
        pa[kc] = *(const bf16x8*)&P[l15 * 76 + kc * 32 + quad * 8];
      for (int ns = 0; ns < 8; ns++)
        for (int kc = 0; kc < 2; kc++) {
          bf16x8 vf = *(const bf16x8*)&Vs[buf][(ns * 16 + l15) * 64 + (((kc * 4 + quad) ^ (l15 & 7)) << 3)];
          o[ns] = mfma16(vf, pa[kc], o[ns]);  // O^T: col=l15=q
        }
      __syncthreads();
    }
    // epilogue: O^T col=l15=q, row(within ns)=quad*4+r -> d = ns*16+quad*4+r
    float inv = 1.0f / lsum;
    int q = qw + l15;
    size_t base = ((size_t)(b * SEQ + q)) * DIN + h * DH + quad * 4;
    for (int ns = 0; ns < 8; ns++) {
      bf16x4 pk;
      for (int r = 0; r < 4; r++) pk[r] = (bf16)(o[ns][r] * inv);
      *(bf16x4*)&Yb[base + ns * 16] = pk;
    }
  }
}

// ---------------- proj GEMM (BK=64, xor-swizzled LDS chunks) ----------------
__global__ __launch_bounds__(256) void gemm_proj_k(const bf16* __restrict__ A, const bf16* __restrict__ BT,
                                                   void* __restrict__ out, const int* __restrict__ flag) {
  __shared__ __align__(16) bf16 As[128 * 64];
  __shared__ __align__(16) bf16 Bs[128 * 64];
  const int K = DIN;
  int m0 = blockIdx.y * 128, n0 = blockIdx.x * 128;
  int tid = threadIdx.x, w = tid >> 6, l = tid & 63;
  int l15 = l & 15, quad = l >> 4;
  int wm = (w & 1) * 64, wn = (w >> 1) * 64;
  bool obf = *flag != 0;
  f32x4 zero = {0.f, 0.f, 0.f, 0.f};
  f32x4 acc[4][4];
  for (int i = 0; i < 4; i++)
    for (int j = 0; j < 4; j++) acc[i][j] = zero;
  int gch = (l & 7) ^ (l >> 3);
  const bf16* Ag = A + (size_t)(m0 + w * 32 + (l >> 3)) * K + gch * 8;
  const bf16* Bg = BT + (size_t)(n0 + w * 32 + (l >> 3)) * K + gch * 8;
  bf16* AsW = As + w * 2048;
  bf16* BsW = Bs + w * 2048;
  for (int k0 = 0; k0 < K; k0 += 64) {
    __syncthreads();
    for (int j = 0; j < 4; j++) async16(Ag + k0 + (size_t)j * 8 * K, AsW + j * 512);
    for (int j = 0; j < 4; j++) async16(Bg + k0 + (size_t)j * 8 * K, BsW + j * 512);
    __syncthreads();
    for (int kk = 0; kk < 2; kk++) {
      bf16x8 af[4], bfv[4];
      for (int i = 0; i < 4; i++)
        af[i] = *(const bf16x8*)&As[(wm + i * 16 + l15) * 64 + (((kk * 4 + quad) ^ (l15 & 7)) << 3)];
      for (int j = 0; j < 4; j++)
        bfv[j] = *(const bf16x8*)&Bs[(wn + j * 16 + l15) * 64 + (((kk * 4 + quad) ^ (l15 & 7)) << 3)];
      for (int i = 0; i < 4; i++)
        for (int j = 0; j < 4; j++) acc[i][j] = mfma16(af[i], bfv[j], acc[i][j]);
    }
  }
  for (int j = 0; j < 4; j++) {
    int col = n0 + wn + j * 16 + l15;
    for (int i = 0; i < 4; i++) {
      int mrow = m0 + wm + i * 16 + quad * 4;
      for (int r = 0; r < 4; r++) {
        size_t idx = (size_t)(mrow + r) * DIN + col;
        float v = acc[i][j][r];
        if (obf)
          ((bf16*)out)[idx] = (bf16)v;
        else
          ((float*)out)[idx] = v;
      }
    }
  }
}

extern "C" void kernel_launch(void* const* d_in, const int* in_sizes, int n_in,
                              void* d_out, int out_size, void* d_ws, size_t ws_size,
                              hipStream_t stream) {
  char* ws = (char*)d_ws;
  int* flag = (int*)ws;
  bf16* Xb = (bf16*)(ws + 256);                                  // 16 MiB, aliased with Yb
  bf16* WqkvT = (bf16*)(ws + 256 + 16777216);                    // 24 MiB
  bf16* WprojT = (bf16*)(ws + 256 + 16777216 + 25165824);        // 8 MiB
  bf16* Qb = (bf16*)(ws + 256 + 16777216 + 25165824 + 8388608);  // 16 MiB each
  bf16* Kb = Qb + (size_t)MM * DIN;
  bf16* Vb = Kb + (size_t)MM * DIN;
  bf16* Vt = Vb + (size_t)MM * DIN;
  bf16* Yb = Xb;  // Xb dead after gemm_qkv

  sniff_k<<<1, 256, 0, stream>>>((const unsigned short*)d_in[0], flag);
  cast_x_k<<<4096, 256, 0, stream>>>(d_in[0], Xb, flag);
  cast_wT_k<<<dim3(192, 64), 256, 0, stream>>>(d_in[1], WqkvT, flag, DIN, N3);
  cast_wT_k<<<dim3(64, 64), 256, 0, stream>>>(d_in[2], WprojT, flag, DIN, DIN);
  gemm_qkv_k<<<dim3(48, 32), 256, 0, stream>>>(Xb, WqkvT, Qb, Kb, Vb);
  rope_k<<<16384, 256, 0, stream>>>(Qb, Kb);
  transpose_v_k<<<dim3(64, 4, 32), 256, 0, stream>>>(Vb, Vt);
  attn_k<<<dim3(32, 16), 256, 0, stream>>>(Qb, Kb, Vt, Yb);
  gemm_proj_k<<<dim3(16, 32), 256, 0, stream>>>(Yb, WprojT, d_out, flag);
}